// Round 19
// baseline (74.503 us; speedup 1.0000x reference)
//
#include <hip/hip_runtime.h>
#include <stdint.h>

// CapsuleLayer dynamic routing — round 19: fused, bf16-packed u, high residency.
// x: [B=256, R=1152, I=8] f32; W: [C=10, R=1152, I=8, O=16] f32
// out: v = [B, C, 1, 1, O=16] f32
//
// After 6 falsified K1 theories, the split is at its ~58us structural floor
// (K1 pinned at 41us for 92MB-write+28MB-read). This round returns to the
// FUSED design with the state-compression learned since r7:
//   r7: BPB=2, f32 u in regs = 88 VGPR, ~7 waves/CU, 73.6us (latency-bound,
//       W L2 stream exposed; W traffic floor at BPB=2 is only ~22us).
//   now: u bf16-packed (36 VGPR for 2 batches x 9k x 4o) + vsum trick (zero
//       logit registers; logit = u . running-sum-of-v, exp(0)=1 at it0)
//       + W float4s consumed immediately for both batches (live range ~2
//       quads, not 32 regs) -> peak ~80 VGPR -> LB(512,3): 3 blocks/CU,
//       24 waves = 3.4x r7's residency. u NEVER touches memory (the split
//       paid 92MB write + 94MB read for it).
// No workspace needed. absmax ~0.0117 (bf16 u path, proven r10-r18).

#define B_ 256
#define C_ 10
#define R_ 1152
#define I_ 8
#define O_ 16
#define T_ 512
#define KPT 9            // R chunks of 128
#define NW 8
#define NITER 3

__device__ __forceinline__ uint32_t bf16_rn(float f) {
    uint32_t u = __builtin_bit_cast(uint32_t, f);
    return (u + 0x7FFFu + ((u >> 16) & 1u)) >> 16;
}
__device__ __forceinline__ uint32_t pack2(float lo, float hi) {
    return bf16_rn(lo) | (bf16_rn(hi) << 16);
}
__device__ __forceinline__ float unlo(uint32_t p) {
    return __builtin_bit_cast(float, p << 16);
}
__device__ __forceinline__ float unhi(uint32_t p) {
    return __builtin_bit_cast(float, p & 0xFFFF0000u);
}

__global__ __launch_bounds__(T_, 3) void capsule_fused_kernel(
    const float* __restrict__ x,   // [B, R, I]
    const float* __restrict__ w,   // [C, R, I, O]
    float* __restrict__ out)       // [B, C, O]
{
    const int wg   = blockIdx.x;       // 1280 blocks, c-major
    const int c    = wg >> 7;          // 128 b-pairs per c
    const int b0   = (wg & 127) * 2;
    const int tid  = threadIdx.x;
    const int lane = tid & 63;
    const int wid  = tid >> 6;
    const int oq   = tid & 3;          // owns outputs [4*oq, 4*oq+4)
    const int rl   = tid >> 2;         // route-node slot within pass [0,128)

    __shared__ float sred[2][NW][4][4];   // per-wave partial s by o-quad
    __shared__ float zred[2][NW];         // per-wave partial Z
    __shared__ float vsum[2][O_];         // running sum of v over iterations

    uint32_t up0[KPT][2], up1[KPT][2];    // u as packed bf16: 36 VGPRs total

    if (tid < 2 * O_) vsum[tid >> 4][tid & 15] = 0.f;

    // ---- u-compute: each W float4 used immediately for BOTH batches ----
    #pragma unroll
    for (int k = 0; k < KPT; ++k) {
        const int r = k * 128 + rl;
        const float4* wb4 = (const float4*)(w + ((size_t)c * R_ + r) * (I_ * O_));
        const float4* xp0 = (const float4*)(x + ((size_t)b0 * R_ + r) * I_);
        const float4* xp1 = (const float4*)(x + ((size_t)(b0 + 1) * R_ + r) * I_);
        const float4 xa0 = xp0[0], xb0 = xp0[1];
        const float4 xa1 = xp1[0], xb1 = xp1[1];
        const float xs0[8] = {xa0.x, xa0.y, xa0.z, xa0.w, xb0.x, xb0.y, xb0.z, xb0.w};
        const float xs1[8] = {xa1.x, xa1.y, xa1.z, xa1.w, xb1.x, xb1.y, xb1.z, xb1.w};
        float a00 = 0.f, a01 = 0.f, a02 = 0.f, a03 = 0.f;
        float a10 = 0.f, a11 = 0.f, a12 = 0.f, a13 = 0.f;
        #pragma unroll
        for (int i = 0; i < I_; ++i) {
            const float4 Wv = wb4[i * 4 + oq];   // short live range
            a00 += xs0[i] * Wv.x; a01 += xs0[i] * Wv.y;
            a02 += xs0[i] * Wv.z; a03 += xs0[i] * Wv.w;
            a10 += xs1[i] * Wv.x; a11 += xs1[i] * Wv.y;
            a12 += xs1[i] * Wv.z; a13 += xs1[i] * Wv.w;
        }
        up0[k][0] = pack2(a00, a01); up0[k][1] = pack2(a02, a03);
        up1[k][0] = pack2(a10, a11); up1[k][1] = pack2(a12, a13);
    }
    __syncthreads();   // vsum init visible

    // ---- routing iterations (no logit state; logit = u . vsum) ----
    #pragma unroll
    for (int it = 0; it < NITER; ++it) {
        float4 vs0 = make_float4(0.f, 0.f, 0.f, 0.f);
        float4 vs1 = vs0;
        if (it > 0) {
            vs0 = *(const float4*)&vsum[0][oq * 4];
            vs1 = *(const float4*)&vsum[1][oq * 4];
        }
        float z0 = 0.f, s00 = 0.f, s01 = 0.f, s02 = 0.f, s03 = 0.f;
        float z1 = 0.f, s10 = 0.f, s11 = 0.f, s12 = 0.f, s13 = 0.f;
        #pragma unroll
        for (int k = 0; k < KPT; ++k) {
            const float u00 = unlo(up0[k][0]), u01 = unhi(up0[k][0]);
            const float u02 = unlo(up0[k][1]), u03 = unhi(up0[k][1]);
            const float u10 = unlo(up1[k][0]), u11 = unhi(up1[k][0]);
            const float u12 = unlo(up1[k][1]), u13 = unhi(up1[k][1]);
            float e0, e1;
            if (it == 0) {
                e0 = 1.f; e1 = 1.f;    // logits all 0 -> uniform c for free
            } else {
                float d0 = u00 * vs0.x + u01 * vs0.y + u02 * vs0.z + u03 * vs0.w;
                float d1 = u10 * vs1.x + u11 * vs1.y + u12 * vs1.z + u13 * vs1.w;
                d0 += __shfl_xor(d0, 1); d1 += __shfl_xor(d1, 1);
                d0 += __shfl_xor(d0, 2); d1 += __shfl_xor(d1, 2);
                e0 = __expf(d0); e1 = __expf(d1);
            }
            z0 += e0; s00 += e0 * u00; s01 += e0 * u01; s02 += e0 * u02; s03 += e0 * u03;
            z1 += e1; s10 += e1 * u10; s11 += e1 * u11; s12 += e1 * u12; s13 += e1 * u13;
        }
        // wave butterfly over the 16 quads (oq kept separate)
        #pragma unroll
        for (int off = 4; off <= 32; off <<= 1) {
            z0 += __shfl_xor(z0, off);   z1 += __shfl_xor(z1, off);
            s00 += __shfl_xor(s00, off); s01 += __shfl_xor(s01, off);
            s02 += __shfl_xor(s02, off); s03 += __shfl_xor(s03, off);
            s10 += __shfl_xor(s10, off); s11 += __shfl_xor(s11, off);
            s12 += __shfl_xor(s12, off); s13 += __shfl_xor(s13, off);
        }
        if (lane < 4) {   // lane == oq here
            sred[0][wid][lane][0] = s00; sred[0][wid][lane][1] = s01;
            sred[0][wid][lane][2] = s02; sred[0][wid][lane][3] = s03;
            sred[1][wid][lane][0] = s10; sred[1][wid][lane][1] = s11;
            sred[1][wid][lane][2] = s12; sred[1][wid][lane][3] = s13;
            if (lane == 0) { zred[0][wid] = z0; zred[1][wid] = z1; }
        }
        __syncthreads();

        // wave 0 finalizes both batches: lanes 0-15 -> b0, 16-31 -> b0+1
        if (wid == 0 && lane < 2 * O_) {
            const int bb = lane >> 4;
            const int o  = lane & 15;
            float S = 0.f, Z = 0.f;
            #pragma unroll
            for (int wv = 0; wv < NW; ++wv) {
                S += sred[bb][wv][o >> 2][o & 3];
                Z += zred[bb][wv];
            }
            const float inv = 1.f / Z;
            const float svn = S * inv;
            float p = svn * svn;   // butterfly within 16-lane group -> |s|^2
            p += __shfl_xor(p, 1);
            p += __shfl_xor(p, 2);
            p += __shfl_xor(p, 4);
            p += __shfl_xor(p, 8);
            const float scale = sqrtf(p) / (1.f + p);
            const float vf = svn * scale;
            vsum[bb][o] += vf;
            if (it == NITER - 1)
                out[((size_t)(b0 + bb) * C_ + c) * O_ + o] = vf;
        }
        if (it != NITER - 1) __syncthreads();   // vsum update visible
    }
}

extern "C" void kernel_launch(void* const* d_in, const int* in_sizes, int n_in,
                              void* d_out, int out_size, void* d_ws, size_t ws_size,
                              hipStream_t stream) {
    const float* x = (const float*)d_in[0];
    const float* w = (const float*)d_in[1];
    float* out = (float*)d_out;
    capsule_fused_kernel<<<dim3(C_ * (B_ / 2)), dim3(T_), 0, stream>>>(x, w, out);
}

// Round 20
// 67.541 us; speedup vs baseline: 1.1031x; 1.1031x over previous
//
#include <hip/hip_runtime.h>
#include <stdint.h>

// CapsuleLayer dynamic routing — round 20: K1 with loads-before-stores.
// x: [B=256, R=1152, I=8] f32; W: [C=10, R=1152, I=8, O=16] f32
// out: v = [B, C, 1, 1, O=16] f32
//
// THEORY: vmcnt retires IN ORDER (cdna4_isa). K1's old loop was
// store(p) -> load x(p+1) -> s_waitcnt for the load = vmcnt(0), which also
// drains the store through its L2 write-allocate (~100s of cycles), every
// pass, every wave. Explains all six prior nulls (occupancy/width/nt/pin/
// contiguity never touched instruction ORDER). In-session evidence: every
// fast stream (K2 5.5TB/s, fillBuffer 6.5TB/s) has no load-after-store;
// every slow one (K1 variants, 2.2-2.9TB/s) interleaves them.
// FIX: 4 batches/block (grid 5760); ALL 16 loads first (8 W + 8 x float4),
// all FMAs, then exactly 2 u32x4 stores at the end. ~90 VGPR, LB(512,3).
// K2 identical to r17 (2-batch u32x4 routing, loads all up-front).
// Fallback: round-10 fused kernel if ws too small.

#define B_ 256
#define C_ 10
#define R_ 1152
#define I_ 8
#define O_ 16
#define T_ 512
#define KPT 9            // R chunks of 128
#define NW 8
#define NITER 3

typedef unsigned int u32x4 __attribute__((ext_vector_type(4)));

__device__ __forceinline__ uint32_t bf16_rn(float f) {
    uint32_t u = __builtin_bit_cast(uint32_t, f);
    return (u + 0x7FFFu + ((u >> 16) & 1u)) >> 16;
}
__device__ __forceinline__ uint32_t pack2(float lo, float hi) {
    return bf16_rn(lo) | (bf16_rn(hi) << 16);
}
__device__ __forceinline__ float unlo(uint32_t p) {
    return __builtin_bit_cast(float, p << 16);
}
__device__ __forceinline__ float unhi(uint32_t p) {
    return __builtin_bit_cast(float, p & 0xFFFF0000u);
}

// ---------------- K1: u[b,c,r,:] = x[b,r,:] @ W[c,r,:,:]  (bf16 packed) ----
// grid 5760 = c(10) x kchunk(9) x btile(64); 4 batches per block.
// u layout (u32x4 units): ((b2*C + c)*KPT + kc)*512 + tid, b2 = b>>1;
//   [0..1] = even batch, [2..3] = odd batch (each pair = 4 bf16 of oq).
__global__ __launch_bounds__(T_, 3) void caps_u_kernel(
    const float* __restrict__ x,
    const float* __restrict__ w,
    u32x4* __restrict__ u)
{
    const int bx  = blockIdx.x;
    const int c   = bx / 576;
    const int kc  = (bx % 576) >> 6;
    const int bt  = bx & 63;
    const int b0  = bt * 4;
    const int tid = threadIdx.x;
    const int oq  = tid & 3;
    const int rl  = tid >> 2;
    const int r   = kc * 128 + rl;

    // ---- ALL loads first: no store precedes any load in this kernel ----
    const float4* wb4 = (const float4*)(w + ((size_t)c * R_ + r) * (I_ * O_));
    const float4 W0 = wb4[0 * 4 + oq], W1 = wb4[1 * 4 + oq];
    const float4 W2 = wb4[2 * 4 + oq], W3 = wb4[3 * 4 + oq];
    const float4 W4 = wb4[4 * 4 + oq], W5 = wb4[5 * 4 + oq];
    const float4 W6 = wb4[6 * 4 + oq], W7 = wb4[7 * 4 + oq];

    float4 XA[4], XB[4];
    #pragma unroll
    for (int bb = 0; bb < 4; ++bb) {
        const float4* xp = (const float4*)(x + ((size_t)(b0 + bb) * R_ + r) * I_);
        XA[bb] = xp[0];
        XB[bb] = xp[1];
    }

    // ---- all compute ----
    uint32_t q[4][2];
    #pragma unroll
    for (int bb = 0; bb < 4; ++bb) {
        const float xs[8] = {XA[bb].x, XA[bb].y, XA[bb].z, XA[bb].w,
                             XB[bb].x, XB[bb].y, XB[bb].z, XB[bb].w};
        float a0, a1, a2, a3;
        a0 = xs[0] * W0.x; a1 = xs[0] * W0.y; a2 = xs[0] * W0.z; a3 = xs[0] * W0.w;
        a0 += xs[1] * W1.x; a1 += xs[1] * W1.y; a2 += xs[1] * W1.z; a3 += xs[1] * W1.w;
        a0 += xs[2] * W2.x; a1 += xs[2] * W2.y; a2 += xs[2] * W2.z; a3 += xs[2] * W2.w;
        a0 += xs[3] * W3.x; a1 += xs[3] * W3.y; a2 += xs[3] * W3.z; a3 += xs[3] * W3.w;
        a0 += xs[4] * W4.x; a1 += xs[4] * W4.y; a2 += xs[4] * W4.z; a3 += xs[4] * W4.w;
        a0 += xs[5] * W5.x; a1 += xs[5] * W5.y; a2 += xs[5] * W5.z; a3 += xs[5] * W5.w;
        a0 += xs[6] * W6.x; a1 += xs[6] * W6.y; a2 += xs[6] * W6.z; a3 += xs[6] * W6.w;
        a0 += xs[7] * W7.x; a1 += xs[7] * W7.y; a2 += xs[7] * W7.z; a3 += xs[7] * W7.w;
        q[bb][0] = pack2(a0, a1);
        q[bb][1] = pack2(a2, a3);
    }

    // ---- stores LAST (2 x u32x4); nothing loads after these ----
    #pragma unroll
    for (int p = 0; p < 2; ++p) {
        const size_t b2 = (size_t)(bt * 2 + p);
        u32x4 qq;
        qq[0] = q[2 * p][0];     qq[1] = q[2 * p][1];
        qq[2] = q[2 * p + 1][0]; qq[3] = q[2 * p + 1][1];
        u[((b2 * C_ + c) * KPT + kc) * T_ + tid] = qq;
    }
}

// ---------------- K2: routing from materialized u (2 batches/block) -------
// block wg2 = b2*C + c (1280 blocks). Thread loads 9 u32x4 (36 bf16 per
// batch) up-front. vsum trick: logit = u . (running sum of v); exp(0)=1 it0.
__global__ __launch_bounds__(T_, 3) void caps_route_kernel(
    const u32x4* __restrict__ u,
    float* __restrict__ out)
{
    const int wg2  = blockIdx.x;       // = b2*C + c
    const int b2   = wg2 / C_;
    const int c    = wg2 % C_;
    const int tid  = threadIdx.x;
    const int lane = tid & 63;
    const int wid  = tid >> 6;
    const int oq   = tid & 3;

    __shared__ float sred[2][NW][4][4];
    __shared__ float zred[2][NW];
    __shared__ float vsum[2][O_];

    u32x4 up[KPT];
    #pragma unroll
    for (int k = 0; k < KPT; ++k)
        up[k] = u[((size_t)wg2 * KPT + k) * T_ + tid];

    if (tid < 2 * O_) vsum[tid >> 4][tid & 15] = 0.f;
    __syncthreads();

    #pragma unroll
    for (int it = 0; it < NITER; ++it) {
        float4 vs0 = make_float4(0.f, 0.f, 0.f, 0.f);
        float4 vs1 = vs0;
        if (it > 0) {
            vs0 = *(const float4*)&vsum[0][oq * 4];
            vs1 = *(const float4*)&vsum[1][oq * 4];
        }
        float z0 = 0.f, s00 = 0.f, s01 = 0.f, s02 = 0.f, s03 = 0.f;
        float z1 = 0.f, s10 = 0.f, s11 = 0.f, s12 = 0.f, s13 = 0.f;
        #pragma unroll
        for (int k = 0; k < KPT; ++k) {
            const float u00 = unlo(up[k][0]), u01 = unhi(up[k][0]);
            const float u02 = unlo(up[k][1]), u03 = unhi(up[k][1]);
            const float u10 = unlo(up[k][2]), u11 = unhi(up[k][2]);
            const float u12 = unlo(up[k][3]), u13 = unhi(up[k][3]);
            float e0, e1;
            if (it == 0) {
                e0 = 1.f; e1 = 1.f;
            } else {
                float d0 = u00 * vs0.x + u01 * vs0.y + u02 * vs0.z + u03 * vs0.w;
                float d1 = u10 * vs1.x + u11 * vs1.y + u12 * vs1.z + u13 * vs1.w;
                d0 += __shfl_xor(d0, 1); d1 += __shfl_xor(d1, 1);
                d0 += __shfl_xor(d0, 2); d1 += __shfl_xor(d1, 2);
                e0 = __expf(d0); e1 = __expf(d1);
            }
            z0 += e0; s00 += e0 * u00; s01 += e0 * u01; s02 += e0 * u02; s03 += e0 * u03;
            z1 += e1; s10 += e1 * u10; s11 += e1 * u11; s12 += e1 * u12; s13 += e1 * u13;
        }
        #pragma unroll
        for (int off = 4; off <= 32; off <<= 1) {
            z0 += __shfl_xor(z0, off);   z1 += __shfl_xor(z1, off);
            s00 += __shfl_xor(s00, off); s01 += __shfl_xor(s01, off);
            s02 += __shfl_xor(s02, off); s03 += __shfl_xor(s03, off);
            s10 += __shfl_xor(s10, off); s11 += __shfl_xor(s11, off);
            s12 += __shfl_xor(s12, off); s13 += __shfl_xor(s13, off);
        }
        if (lane < 4) {   // lane == oq
            sred[0][wid][lane][0] = s00; sred[0][wid][lane][1] = s01;
            sred[0][wid][lane][2] = s02; sred[0][wid][lane][3] = s03;
            sred[1][wid][lane][0] = s10; sred[1][wid][lane][1] = s11;
            sred[1][wid][lane][2] = s12; sred[1][wid][lane][3] = s13;
            if (lane == 0) { zred[0][wid] = z0; zred[1][wid] = z1; }
        }
        __syncthreads();

        // wave 0 finalizes both batches: lanes 0-15 -> even b, 16-31 -> odd b
        if (wid == 0 && lane < 2 * O_) {
            const int bb = lane >> 4;
            const int o  = lane & 15;
            float S = 0.f, Z = 0.f;
            #pragma unroll
            for (int wv = 0; wv < NW; ++wv) {
                S += sred[bb][wv][o >> 2][o & 3];
                Z += zred[bb][wv];
            }
            const float inv = 1.f / Z;
            const float svn = S * inv;
            float p = svn * svn;   // butterfly within 16-lane group -> |s|^2
            p += __shfl_xor(p, 1);
            p += __shfl_xor(p, 2);
            p += __shfl_xor(p, 4);
            p += __shfl_xor(p, 8);
            const float scale = sqrtf(p) / (1.f + p);
            const float vf = svn * scale;
            vsum[bb][o] += vf;
            if (it == NITER - 1)
                out[((size_t)(b2 * 2 + bb) * C_ + c) * O_ + o] = vf;
        }
        if (it != NITER - 1) __syncthreads();
    }
}

// ---------------- Fallback: round-10 fused kernel (proven) ----------------
#define BPB 4
#define RPP 128

__global__ __launch_bounds__(T_, 2) void capsule_fused_kernel(
    const float* __restrict__ x,
    const float* __restrict__ w,
    float* __restrict__ out)
{
    const int wg   = blockIdx.x;
    const int c    = wg >> 6;
    const int b0   = (wg & 63) * BPB;
    const int tid  = threadIdx.x;
    const int lane = tid & 63;
    const int wid  = tid >> 6;
    const int oq   = tid & 3;
    const int rl   = tid >> 2;

    __shared__ float sred[BPB][NW][4][4];
    __shared__ float zred[BPB][NW];
    __shared__ float vsum[BPB][O_];

    uint32_t up[BPB][KPT][2];

    if (tid < BPB * O_) vsum[tid >> 4][tid & 15] = 0.f;

    #pragma unroll
    for (int k = 0; k < KPT; ++k) {
        const int r = k * RPP + rl;
        const float4* wb4 = (const float4*)(w + ((size_t)c * R_ + r) * (I_ * O_));
        float4 W0 = wb4[0 * 4 + oq], W1 = wb4[1 * 4 + oq];
        float4 W2 = wb4[2 * 4 + oq], W3 = wb4[3 * 4 + oq];
        float4 W4 = wb4[4 * 4 + oq], W5 = wb4[5 * 4 + oq];
        float4 W6 = wb4[6 * 4 + oq], W7 = wb4[7 * 4 + oq];
        #pragma unroll
        for (int bb = 0; bb < BPB; ++bb) {
            const float4* xp = (const float4*)(x + ((size_t)(b0 + bb) * R_ + r) * I_);
            const float4 xa = xp[0];
            const float4 xb = xp[1];
            float a0, a1, a2, a3;
            a0 = xa.x * W0.x; a1 = xa.x * W0.y; a2 = xa.x * W0.z; a3 = xa.x * W0.w;
            a0 += xa.y * W1.x; a1 += xa.y * W1.y; a2 += xa.y * W1.z; a3 += xa.y * W1.w;
            a0 += xa.z * W2.x; a1 += xa.z * W2.y; a2 += xa.z * W2.z; a3 += xa.z * W2.w;
            a0 += xa.w * W3.x; a1 += xa.w * W3.y; a2 += xa.w * W3.z; a3 += xa.w * W3.w;
            a0 += xb.x * W4.x; a1 += xb.x * W4.y; a2 += xb.x * W4.z; a3 += xb.x * W4.w;
            a0 += xb.y * W5.x; a1 += xb.y * W5.y; a2 += xb.y * W5.z; a3 += xb.y * W5.w;
            a0 += xb.z * W6.x; a1 += xb.z * W6.y; a2 += xb.z * W6.z; a3 += xb.z * W6.w;
            a0 += xb.w * W7.x; a1 += xb.w * W7.y; a2 += xb.w * W7.z; a3 += xb.w * W7.w;
            up[bb][k][0] = pack2(a0, a1);
            up[bb][k][1] = pack2(a2, a3);
        }
    }
    __syncthreads();

    #pragma unroll
    for (int it = 0; it < NITER; ++it) {
        float zz[BPB], ss[BPB][4];
        #pragma unroll
        for (int bb = 0; bb < BPB; ++bb) {
            float4 vs = make_float4(0.f, 0.f, 0.f, 0.f);
            if (it > 0) vs = *(const float4*)&vsum[bb][oq * 4];
            float z = 0.f, s0 = 0.f, s1 = 0.f, s2 = 0.f, s3 = 0.f;
            #pragma unroll
            for (int k = 0; k < KPT; ++k) {
                const float u0 = unlo(up[bb][k][0]);
                const float u1 = unhi(up[bb][k][0]);
                const float u2 = unlo(up[bb][k][1]);
                const float u3 = unhi(up[bb][k][1]);
                float e;
                if (it == 0) {
                    e = 1.f;
                } else {
                    float d = u0 * vs.x + u1 * vs.y + u2 * vs.z + u3 * vs.w;
                    d += __shfl_xor(d, 1);
                    d += __shfl_xor(d, 2);
                    e = __expf(d);
                }
                z += e;
                s0 += e * u0; s1 += e * u1; s2 += e * u2; s3 += e * u3;
            }
            zz[bb] = z;
            ss[bb][0] = s0; ss[bb][1] = s1; ss[bb][2] = s2; ss[bb][3] = s3;
        }
        #pragma unroll
        for (int off = 4; off <= 32; off <<= 1) {
            #pragma unroll
            for (int bb = 0; bb < BPB; ++bb) {
                zz[bb] += __shfl_xor(zz[bb], off);
                ss[bb][0] += __shfl_xor(ss[bb][0], off);
                ss[bb][1] += __shfl_xor(ss[bb][1], off);
                ss[bb][2] += __shfl_xor(ss[bb][2], off);
                ss[bb][3] += __shfl_xor(ss[bb][3], off);
            }
        }
        if (lane < 4) {
            #pragma unroll
            for (int bb = 0; bb < BPB; ++bb) {
                sred[bb][wid][lane][0] = ss[bb][0];
                sred[bb][wid][lane][1] = ss[bb][1];
                sred[bb][wid][lane][2] = ss[bb][2];
                sred[bb][wid][lane][3] = ss[bb][3];
                if (lane == 0) zred[bb][wid] = zz[bb];
            }
        }
        __syncthreads();

        if (wid == 0) {
            const int bb = lane >> 4;
            const int o  = lane & 15;
            float S = 0.f, Z = 0.f;
            #pragma unroll
            for (int wv = 0; wv < NW; ++wv) {
                S += sred[bb][wv][o >> 2][o & 3];
                Z += zred[bb][wv];
            }
            const float inv = 1.f / Z;
            const float svn = S * inv;
            float p = svn * svn;
            p += __shfl_xor(p, 1);
            p += __shfl_xor(p, 2);
            p += __shfl_xor(p, 4);
            p += __shfl_xor(p, 8);
            const float scale = sqrtf(p) / (1.f + p);
            const float vf = svn * scale;
            vsum[bb][o] += vf;
            if (it == NITER - 1)
                out[((size_t)(b0 + bb) * C_ + c) * O_ + o] = vf;
        }
        if (it != NITER - 1) __syncthreads();
    }
}

extern "C" void kernel_launch(void* const* d_in, const int* in_sizes, int n_in,
                              void* d_out, int out_size, void* d_ws, size_t ws_size,
                              hipStream_t stream) {
    const float* x = (const float*)d_in[0];
    const float* w = (const float*)d_in[1];
    float* out = (float*)d_out;

    const size_t u_bytes = (size_t)(B_ / 2) * C_ * KPT * T_ * 16;   // 94,371,840
    if (ws_size >= u_bytes) {
        u32x4* u = (u32x4*)d_ws;
        caps_u_kernel<<<dim3(C_ * KPT * 64), dim3(T_), 0, stream>>>(x, w, u);
        caps_route_kernel<<<dim3((B_ / 2) * C_), dim3(T_), 0, stream>>>(u, out);
    } else {
        capsule_fused_kernel<<<dim3(C_ * (B_ / BPB)), dim3(T_), 0, stream>>>(x, w, out);
    }
}

// Round 21
// 61.782 us; speedup vs baseline: 1.2059x; 1.0932x over previous
//
#include <hip/hip_runtime.h>
#include <stdint.h>

// CapsuleLayer dynamic routing — FINAL (= round 13, session best: 60.93us).
// x: [B=256, R=1152, I=8] f32; W: [C=10, R=1152, I=8, O=16] f32
// out: v = [B, C, 1, 1, O=16] f32
//
// Design: two-kernel split. K1 materializes u = x@W in bf16 (94MB, d_ws);
// K2 routes from u (3 iters fully in-register, vsum trick: logit = u .
// running-sum-of-v, so no logit state; exp(0)=1 at it0 = uniform-c free).
// Session findings baked in: quad-of-lanes owns a route node (dwordx4 W
// loads, 64B-line coalesced — float2 variant was 2x slower at same bytes);
// u bf16-packed (halves u traffic; absmax 0.0117 < 1.7e-2 threshold);
// K2 reads are sequential per block (5.5TB/s, ~88% of streaming ceiling).
// K1 is pinned at ~41us (2.9TB/s mixed 28MB-read+92MB-write) — 7 structural
// levers (occupancy, VMEM count, store width, nt, W-pinning, contiguity,
// load/store order) all null; accepted as this decomposition's floor.
// Fallback: round-10 fused kernel (70.6us) if ws too small.

#define B_ 256
#define C_ 10
#define R_ 1152
#define I_ 8
#define O_ 16
#define T_ 512
#define KPT 9            // R chunks of 128
#define NW 8
#define NITER 3

typedef float f32x4 __attribute__((ext_vector_type(4)));

__device__ __forceinline__ uint32_t bf16_rn(float f) {
    uint32_t u = __builtin_bit_cast(uint32_t, f);
    return (u + 0x7FFFu + ((u >> 16) & 1u)) >> 16;
}
__device__ __forceinline__ uint32_t pack2(float lo, float hi) {
    return bf16_rn(lo) | (bf16_rn(hi) << 16);
}
__device__ __forceinline__ float unlo(uint32_t p) {
    return __builtin_bit_cast(float, p << 16);
}
__device__ __forceinline__ float unhi(uint32_t p) {
    return __builtin_bit_cast(float, p & 0xFFFF0000u);
}

// ---------------- K1: u[b,c,r,:] = x[b,r,:] @ W[c,r,:,:]  (bf16 packed) ----
// grid 2880 = c(10) x kchunk(9) x btile(32). T=512; thread = (rl=tid>>2, oq=tid&3).
__global__ __launch_bounds__(T_, 3) void caps_u_kernel(
    const float* __restrict__ x,
    const float* __restrict__ w,
    uint2* __restrict__ u)
{
    const int bx  = blockIdx.x;
    const int c   = bx / 288;
    const int kc  = (bx % 288) >> 5;
    const int bt  = bx & 31;
    const int tid = threadIdx.x;
    const int oq  = tid & 3;
    const int rl  = tid >> 2;
    const int r   = kc * 128 + rl;

    // base points at W[c, r, i=0, oq*4]; the 8 i-rows are 64B apart.
    const float* wbase = w + ((size_t)c * R_ + r) * (I_ * O_) + oq * 4;
    f32x4 W0, W1, W2, W3, W4, W5, W6, W7;
    asm volatile("global_load_dwordx4 %0, %1, off"            : "=v"(W0) : "v"(wbase));
    asm volatile("global_load_dwordx4 %0, %1, off offset:64"  : "=v"(W1) : "v"(wbase));
    asm volatile("global_load_dwordx4 %0, %1, off offset:128" : "=v"(W2) : "v"(wbase));
    asm volatile("global_load_dwordx4 %0, %1, off offset:192" : "=v"(W3) : "v"(wbase));
    asm volatile("global_load_dwordx4 %0, %1, off offset:256" : "=v"(W4) : "v"(wbase));
    asm volatile("global_load_dwordx4 %0, %1, off offset:320" : "=v"(W5) : "v"(wbase));
    asm volatile("global_load_dwordx4 %0, %1, off offset:384" : "=v"(W6) : "v"(wbase));
    asm volatile("global_load_dwordx4 %0, %1, off offset:448" : "=v"(W7) : "v"(wbase));
    asm volatile("s_waitcnt vmcnt(0)"
                 : "+v"(W0), "+v"(W1), "+v"(W2), "+v"(W3),
                   "+v"(W4), "+v"(W5), "+v"(W6), "+v"(W7));

    #pragma unroll 4
    for (int bb = 0; bb < 8; ++bb) {
        const int b = bt * 8 + bb;
        const float4* xp = (const float4*)(x + ((size_t)b * R_ + r) * I_);
        const float4 xa = xp[0];
        const float4 xb = xp[1];
        float a0, a1, a2, a3;
        a0 = xa.x * W0[0]; a1 = xa.x * W0[1]; a2 = xa.x * W0[2]; a3 = xa.x * W0[3];
        a0 += xa.y * W1[0]; a1 += xa.y * W1[1]; a2 += xa.y * W1[2]; a3 += xa.y * W1[3];
        a0 += xa.z * W2[0]; a1 += xa.z * W2[1]; a2 += xa.z * W2[2]; a3 += xa.z * W2[3];
        a0 += xa.w * W3[0]; a1 += xa.w * W3[1]; a2 += xa.w * W3[2]; a3 += xa.w * W3[3];
        a0 += xb.x * W4[0]; a1 += xb.x * W4[1]; a2 += xb.x * W4[2]; a3 += xb.x * W4[3];
        a0 += xb.y * W5[0]; a1 += xb.y * W5[1]; a2 += xb.y * W5[2]; a3 += xb.y * W5[3];
        a0 += xb.z * W6[0]; a1 += xb.z * W6[1]; a2 += xb.z * W6[2]; a3 += xb.z * W6[3];
        a0 += xb.w * W7[0]; a1 += xb.w * W7[1]; a2 += xb.w * W7[2]; a3 += xb.w * W7[3];
        u[(((size_t)b * C_ + c) * KPT + kc) * T_ + tid] =
            make_uint2(pack2(a0, a1), pack2(a2, a3));
    }
}

// ---------------- K2: routing from materialized u ----------------
// One block per (b,c); wg = b*C + c matches u layout -> sequential reads.
__global__ __launch_bounds__(T_, 4) void caps_route_kernel(
    const uint2* __restrict__ u,
    float* __restrict__ out)
{
    const int wg   = blockIdx.x;       // = b*C + c
    const int tid  = threadIdx.x;
    const int lane = tid & 63;
    const int wid  = tid >> 6;
    const int oq   = tid & 3;

    __shared__ float sred[NW][4][4];
    __shared__ float zred[NW];
    __shared__ float vsum[O_];

    uint2 up[KPT];
    #pragma unroll
    for (int k = 0; k < KPT; ++k)
        up[k] = u[((size_t)wg * KPT + k) * T_ + tid];

    if (tid < O_) vsum[tid] = 0.f;
    __syncthreads();

    #pragma unroll
    for (int it = 0; it < NITER; ++it) {
        float4 vs = make_float4(0.f, 0.f, 0.f, 0.f);
        if (it > 0) vs = *(const float4*)&vsum[oq * 4];
        float z = 0.f, s0 = 0.f, s1 = 0.f, s2 = 0.f, s3 = 0.f;
        #pragma unroll
        for (int k = 0; k < KPT; ++k) {
            const float u0 = unlo(up[k].x);
            const float u1 = unhi(up[k].x);
            const float u2 = unlo(up[k].y);
            const float u3 = unhi(up[k].y);
            float e;
            if (it == 0) {
                e = 1.f;
            } else {
                float d = u0 * vs.x + u1 * vs.y + u2 * vs.z + u3 * vs.w;
                d += __shfl_xor(d, 1);    // quad-reduce over the 4 o-quads
                d += __shfl_xor(d, 2);
                e = __expf(d);
            }
            z += e;
            s0 += e * u0; s1 += e * u1; s2 += e * u2; s3 += e * u3;
        }
        #pragma unroll
        for (int off = 4; off <= 32; off <<= 1) {
            z  += __shfl_xor(z, off);
            s0 += __shfl_xor(s0, off);
            s1 += __shfl_xor(s1, off);
            s2 += __shfl_xor(s2, off);
            s3 += __shfl_xor(s3, off);
        }
        if (lane < 4) {   // lane == oq
            sred[wid][lane][0] = s0;
            sred[wid][lane][1] = s1;
            sred[wid][lane][2] = s2;
            sred[wid][lane][3] = s3;
            if (lane == 0) zred[wid] = z;
        }
        __syncthreads();

        if (wid == 0 && lane < O_) {
            float S = 0.f, Z = 0.f;
            #pragma unroll
            for (int wv = 0; wv < NW; ++wv) {
                S += sred[wv][lane >> 2][lane & 3];
                Z += zred[wv];
            }
            const float inv = 1.f / Z;
            const float svn = S * inv;
            float p = svn * svn;
            p += __shfl_xor(p, 1);
            p += __shfl_xor(p, 2);
            p += __shfl_xor(p, 4);
            p += __shfl_xor(p, 8);
            const float scale = sqrtf(p) / (1.f + p);
            const float vf = svn * scale;
            vsum[lane] += vf;
            if (it == NITER - 1)
                out[(size_t)wg * O_ + lane] = vf;
        }
        if (it != NITER - 1) __syncthreads();
    }
}

// ---------------- Fallback: round-10 fused kernel (proven) ----------------
#define BPB 4
#define RPP 128

__global__ __launch_bounds__(T_, 2) void capsule_fused_kernel(
    const float* __restrict__ x,
    const float* __restrict__ w,
    float* __restrict__ out)
{
    const int wg   = blockIdx.x;
    const int c    = wg >> 6;
    const int b0   = (wg & 63) * BPB;
    const int tid  = threadIdx.x;
    const int lane = tid & 63;
    const int wid  = tid >> 6;
    const int oq   = tid & 3;
    const int rl   = tid >> 2;

    __shared__ float sred[BPB][NW][4][4];
    __shared__ float zred[BPB][NW];
    __shared__ float vsum[BPB][O_];

    uint32_t up[BPB][KPT][2];

    if (tid < BPB * O_) vsum[tid >> 4][tid & 15] = 0.f;

    #pragma unroll
    for (int k = 0; k < KPT; ++k) {
        const int r = k * RPP + rl;
        const float4* wb4 = (const float4*)(w + ((size_t)c * R_ + r) * (I_ * O_));
        float4 W0 = wb4[0 * 4 + oq], W1 = wb4[1 * 4 + oq];
        float4 W2 = wb4[2 * 4 + oq], W3 = wb4[3 * 4 + oq];
        float4 W4 = wb4[4 * 4 + oq], W5 = wb4[5 * 4 + oq];
        float4 W6 = wb4[6 * 4 + oq], W7 = wb4[7 * 4 + oq];
        #pragma unroll
        for (int bb = 0; bb < BPB; ++bb) {
            const float4* xp = (const float4*)(x + ((size_t)(b0 + bb) * R_ + r) * I_);
            const float4 xa = xp[0];
            const float4 xb = xp[1];
            float a0, a1, a2, a3;
            a0 = xa.x * W0.x; a1 = xa.x * W0.y; a2 = xa.x * W0.z; a3 = xa.x * W0.w;
            a0 += xa.y * W1.x; a1 += xa.y * W1.y; a2 += xa.y * W1.z; a3 += xa.y * W1.w;
            a0 += xa.z * W2.x; a1 += xa.z * W2.y; a2 += xa.z * W2.z; a3 += xa.z * W2.w;
            a0 += xa.w * W3.x; a1 += xa.w * W3.y; a2 += xa.w * W3.z; a3 += xa.w * W3.w;
            a0 += xb.x * W4.x; a1 += xb.x * W4.y; a2 += xb.x * W4.z; a3 += xb.x * W4.w;
            a0 += xb.y * W5.x; a1 += xb.y * W5.y; a2 += xb.y * W5.z; a3 += xb.y * W5.w;
            a0 += xb.z * W6.x; a1 += xb.z * W6.y; a2 += xb.z * W6.z; a3 += xb.z * W6.w;
            a0 += xb.w * W7.x; a1 += xb.w * W7.y; a2 += xb.w * W7.z; a3 += xb.w * W7.w;
            up[bb][k][0] = pack2(a0, a1);
            up[bb][k][1] = pack2(a2, a3);
        }
    }
    __syncthreads();

    #pragma unroll
    for (int it = 0; it < NITER; ++it) {
        float zz[BPB], ss[BPB][4];
        #pragma unroll
        for (int bb = 0; bb < BPB; ++bb) {
            float4 vs = make_float4(0.f, 0.f, 0.f, 0.f);
            if (it > 0) vs = *(const float4*)&vsum[bb][oq * 4];
            float z = 0.f, s0 = 0.f, s1 = 0.f, s2 = 0.f, s3 = 0.f;
            #pragma unroll
            for (int k = 0; k < KPT; ++k) {
                const float u0 = unlo(up[bb][k][0]);
                const float u1 = unhi(up[bb][k][0]);
                const float u2 = unlo(up[bb][k][1]);
                const float u3 = unhi(up[bb][k][1]);
                float e;
                if (it == 0) {
                    e = 1.f;
                } else {
                    float d = u0 * vs.x + u1 * vs.y + u2 * vs.z + u3 * vs.w;
                    d += __shfl_xor(d, 1);
                    d += __shfl_xor(d, 2);
                    e = __expf(d);
                }
                z += e;
                s0 += e * u0; s1 += e * u1; s2 += e * u2; s3 += e * u3;
            }
            zz[bb] = z;
            ss[bb][0] = s0; ss[bb][1] = s1; ss[bb][2] = s2; ss[bb][3] = s3;
        }
        #pragma unroll
        for (int off = 4; off <= 32; off <<= 1) {
            #pragma unroll
            for (int bb = 0; bb < BPB; ++bb) {
                zz[bb] += __shfl_xor(zz[bb], off);
                ss[bb][0] += __shfl_xor(ss[bb][0], off);
                ss[bb][1] += __shfl_xor(ss[bb][1], off);
                ss[bb][2] += __shfl_xor(ss[bb][2], off);
                ss[bb][3] += __shfl_xor(ss[bb][3], off);
            }
        }
        if (lane < 4) {
            #pragma unroll
            for (int bb = 0; bb < BPB; ++bb) {
                sred[bb][wid][lane][0] = ss[bb][0];
                sred[bb][wid][lane][1] = ss[bb][1];
                sred[bb][wid][lane][2] = ss[bb][2];
                sred[bb][wid][lane][3] = ss[bb][3];
                if (lane == 0) zred[bb][wid] = zz[bb];
            }
        }
        __syncthreads();

        if (wid == 0) {
            const int bb = lane >> 4;
            const int o  = lane & 15;
            float S = 0.f, Z = 0.f;
            #pragma unroll
            for (int wv = 0; wv < NW; ++wv) {
                S += sred[bb][wv][o >> 2][o & 3];
                Z += zred[bb][wv];
            }
            const float inv = 1.f / Z;
            const float svn = S * inv;
            float p = svn * svn;
            p += __shfl_xor(p, 1);
            p += __shfl_xor(p, 2);
            p += __shfl_xor(p, 4);
            p += __shfl_xor(p, 8);
            const float scale = sqrtf(p) / (1.f + p);
            const float vf = svn * scale;
            vsum[bb][o] += vf;
            if (it == NITER - 1)
                out[((size_t)(b0 + bb) * C_ + c) * O_ + o] = vf;
        }
        if (it != NITER - 1) __syncthreads();
    }
}

extern "C" void kernel_launch(void* const* d_in, const int* in_sizes, int n_in,
                              void* d_out, int out_size, void* d_ws, size_t ws_size,
                              hipStream_t stream) {
    const float* x = (const float*)d_in[0];
    const float* w = (const float*)d_in[1];
    float* out = (float*)d_out;

    const size_t u_bytes = (size_t)B_ * C_ * KPT * T_ * 8;   // 94,371,840
    if (ws_size >= u_bytes) {
        uint2* u = (uint2*)d_ws;
        caps_u_kernel<<<dim3(C_ * KPT * 32), dim3(T_), 0, stream>>>(x, w, u);
        caps_route_kernel<<<dim3(B_ * C_), dim3(T_), 0, stream>>>(u, out);
    } else {
        capsule_fused_kernel<<<dim3(C_ * (B_ / BPB)), dim3(T_), 0, stream>>>(x, w, out);
    }
}